// Round 2
// baseline (1037.400 us; speedup 1.0000x reference)
//
#include <hip/hip_runtime.h>
#include <hip/hip_bf16.h>

// VQ quantize. input [8,64,64,256] f32 -> flatten [M=32768, K=256]
// embed [K=256, N=4096] f32. Outputs in d_out (f32):
//   quantize [8388608], diff [1], embed_ind [32768] (as float)
//
// Strategy: bf16-MFMA approximate distance GEMM (pass 1: per-row approx min),
// pass 2: same GEMM + rigorous-bound threshold -> exact f32 rescore of the
// few candidate codes -> exact argmin. Fallback to f32 VALU path if ws small.

#define M_ROWS 32768
#define K_DIM 256
#define N_CODES 4096

typedef __attribute__((ext_vector_type(8))) short short8v;
typedef __attribute__((ext_vector_type(4))) float f32x4;

__device__ inline unsigned long long packKey(float d, int idx) {
    unsigned u = __float_as_uint(d);
    u = (u & 0x80000000u) ? ~u : (u | 0x80000000u);
    return ((unsigned long long)u << 32) | (unsigned)idx;
}
__device__ inline float unpackDist(unsigned long long k) {
    unsigned u = (unsigned)(k >> 32);
    u = (u & 0x80000000u) ? (u & 0x7FFFFFFFu) : ~u;
    return __uint_as_float(u);
}
__device__ inline unsigned short f2bf(float x) {
    __hip_bfloat16 h = __float2bfloat16(x);
    return *reinterpret_cast<unsigned short*>(&h);
}

// ---------------- Kernel: transpose E -> Et [N][K] f32 + Ethi [N][K] bf16 ---
__global__ void transpose_kernel(const float* __restrict__ E,
                                 float* __restrict__ Et,
                                 unsigned short* __restrict__ Ethi) {
    __shared__ float tile[64][65];
    const int kb = blockIdx.x & 3;    // 4 k-tiles of 64
    const int jb = blockIdx.x >> 2;   // 64 j-tiles of 64
    const int t = threadIdx.x;
#pragma unroll
    for (int it = 0; it < 16; ++it) {
        int linear = it * 256 + t;
        int kk = linear >> 6, jj = linear & 63;  // jj = t&63 (coalesced read)
        tile[kk][jj] = E[(size_t)(kb * 64 + kk) * N_CODES + jb * 64 + jj];
    }
    __syncthreads();
#pragma unroll
    for (int it = 0; it < 16; ++it) {
        int linear = it * 256 + t;
        int jj = linear >> 6, kk = linear & 63;  // kk = t&63 (coalesced write)
        float v = tile[kk][jj];
        size_t o = (size_t)(jb * 64 + jj) * K_DIM + kb * 64 + kk;
        Et[o] = v;
        Ethi[o] = f2bf(v);
    }
}

// ---------------- Kernel: norms from Et + max norm ----------------
__global__ void nrm_et_kernel(const float* __restrict__ Et,
                              float* __restrict__ nrm,
                              float* __restrict__ maxnrm) {
    const int l = threadIdx.x & 63;
    const int j = blockIdx.x * 4 + (threadIdx.x >> 6);  // 1024 blocks * 4 waves
    float4 v = *(const float4*)&Et[(size_t)j * K_DIM + l * 4];
    float s = v.x * v.x;
    s = fmaf(v.y, v.y, s); s = fmaf(v.z, v.z, s); s = fmaf(v.w, v.w, s);
#pragma unroll
    for (int sh = 32; sh >= 1; sh >>= 1) s += __shfl_xor(s, sh, 64);
    if (l == 0) {
        nrm[j] = s;
        atomicMax((int*)maxnrm, __float_as_int(s));  // positive floats: int cmp ok
    }
}

// ---------------- Kernel: split F -> Fhi bf16 + per-row threshold add ------
__global__ void splitF_kernel(const float* __restrict__ F,
                              unsigned short* __restrict__ Fhi,
                              float* __restrict__ thrAdd,
                              const float* __restrict__ maxnrm) {
    const int l = threadIdx.x & 63;
    const int row = blockIdx.x * 4 + (threadIdx.x >> 6);  // 8192 blocks
    float4 v = *(const float4*)&F[(size_t)row * K_DIM + l * 4];
    ushort4 h;
    h.x = f2bf(v.x); h.y = f2bf(v.y); h.z = f2bf(v.z); h.w = f2bf(v.w);
    *(ushort4*)&Fhi[(size_t)row * K_DIM + l * 4] = h;
    float s = v.x * v.x;
    s = fmaf(v.y, v.y, s); s = fmaf(v.z, v.z, s); s = fmaf(v.w, v.w, s);
#pragma unroll
    for (int sh = 32; sh >= 1; sh >>= 1) s += __shfl_xor(s, sh, 64);
    if (l == 0) {
        // 2*Delta = 2 * [2*(2^-7+2^-16)*||x||*maxE] ; + slack for f32 accum noise
        thrAdd[row] = 0.0314f * sqrtf(s) * sqrtf(maxnrm[0]) + 0.05f;
    }
}

// ---------------- bf16 MFMA GEMM + argmin / candidate rescore ----------------
// 128x128 tile, BK=64, 4 waves (2x2), mfma_f32_16x16x32_bf16, 4x4 frags/wave.
// LDS staged via global_load_lds w=16 with source pre-swizzle chunk^=(row&7).
template<int PASS>
__global__ __launch_bounds__(256, 2) void gemm_bf16_kernel(
    const unsigned short* __restrict__ Fhi,   // [M][K] bf16
    const unsigned short* __restrict__ Ethi,  // [N][K] bf16
    const float* __restrict__ nrm,            // [N]
    const float* __restrict__ thrAdd,         // [M]  (pass2)
    const unsigned long long* __restrict__ keysIn,  // [M] approx keys (pass2)
    unsigned long long* __restrict__ keysOut,       // [M]
    const float* __restrict__ Fx,             // [M][K] f32 (pass2 exact)
    const float* __restrict__ Et)             // [N][K] f32 (pass2 exact)
{
    __shared__ unsigned short sA[128 * 64];
    __shared__ unsigned short sB[128 * 64];
    const int tid = threadIdx.x;
    const int l = tid & 63;
    const int wid = tid >> 6;
    const int bx = blockIdx.x & 31, by = blockIdx.x >> 5;
    const int bm0 = by * 128, bn0 = bx * 128;
    const int wm = wid >> 1, wn = wid & 1;

    f32x4 acc[4][4];
#pragma unroll
    for (int mi = 0; mi < 4; ++mi)
#pragma unroll
        for (int ni = 0; ni < 4; ++ni) acc[mi][ni] = (f32x4){0.f, 0.f, 0.f, 0.f};

    const int srow = l >> 3;            // row within 8-row issue group
    const int kch = (l & 7) ^ srow;     // swizzled 16B chunk (involution)

    for (int kt = 0; kt < 4; ++kt) {
        const int k0 = kt * 64;
#pragma unroll
        for (int i = 0; i < 4; ++i) {
            const int q = wid * 4 + i;          // 0..15, rows q*8..q*8+7
            const int rowA = q * 8 + srow;
            __builtin_amdgcn_global_load_lds(
                (const __attribute__((address_space(1))) unsigned int*)
                    (Fhi + (size_t)(bm0 + rowA) * K_DIM + k0 + kch * 8),
                (__attribute__((address_space(3))) unsigned int*)(&sA[q * 512]),
                16, 0, 0);
            __builtin_amdgcn_global_load_lds(
                (const __attribute__((address_space(1))) unsigned int*)
                    (Ethi + (size_t)(bn0 + rowA) * K_DIM + k0 + kch * 8),
                (__attribute__((address_space(3))) unsigned int*)(&sB[q * 512]),
                16, 0, 0);
        }
        __syncthreads();   // compiler drains vmcnt(0) before barrier

#pragma unroll
        for (int s = 0; s < 2; ++s) {   // two 32-k slices
            short8v af[4], bfv[4];
#pragma unroll
            for (int mi = 0; mi < 4; ++mi) {
                int row = wm * 64 + mi * 16 + (l & 15);
                int ch = (s * 4 + (l >> 4)) ^ (l & 7);
                af[mi] = *(const short8v*)&sA[row * 64 + ch * 8];
            }
#pragma unroll
            for (int ni = 0; ni < 4; ++ni) {
                int col = wn * 64 + ni * 16 + (l & 15);
                int ch = (s * 4 + (l >> 4)) ^ (l & 7);
                bfv[ni] = *(const short8v*)&sB[col * 64 + ch * 8];
            }
#pragma unroll
            for (int mi = 0; mi < 4; ++mi)
#pragma unroll
                for (int ni = 0; ni < 4; ++ni)
                    acc[mi][ni] = __builtin_amdgcn_mfma_f32_16x16x32_bf16(
                        af[mi], bfv[ni], acc[mi][ni], 0, 0, 0);
        }
        __syncthreads();
    }

    float nrmv[4];
#pragma unroll
    for (int ni = 0; ni < 4; ++ni)
        nrmv[ni] = nrm[bn0 + wn * 64 + ni * 16 + (l & 15)];

    if (PASS == 1) {
        // per-row approx argmin over this block's 128 codes -> atomicMin
#pragma unroll
        for (int mi = 0; mi < 4; ++mi)
#pragma unroll
            for (int rr = 0; rr < 4; ++rr) {
                int rg = bm0 + wm * 64 + mi * 16 + (l >> 4) * 4 + rr;
                float best = INFINITY; int bc = 0;
#pragma unroll
                for (int ni = 0; ni < 4; ++ni) {
                    float d = fmaf(-2.f, acc[mi][ni][rr], nrmv[ni]);
                    if (d < best) { best = d; bc = bn0 + wn * 64 + ni * 16 + (l & 15); }
                }
                unsigned long long key = packKey(best, bc);
#pragma unroll
                for (int sh = 1; sh < 16; sh <<= 1) {
                    unsigned long long o = __shfl_xor(key, sh, 64);
                    if (o < key) key = o;
                }
                if ((l & 15) == 0) atomicMin(&keysOut[rg], key);
            }
    } else {
        // candidates within rigorous bound of approx min -> exact f32 rescore
#pragma unroll
        for (int mi = 0; mi < 4; ++mi)
#pragma unroll
            for (int rr = 0; rr < 4; ++rr) {
                int rg = bm0 + wm * 64 + mi * 16 + (l >> 4) * 4 + rr;
                float thr = unpackDist(keysIn[rg]) + thrAdd[rg];
#pragma unroll
                for (int ni = 0; ni < 4; ++ni) {
                    float d = fmaf(-2.f, acc[mi][ni][rr], nrmv[ni]);
                    if (d <= thr) {
                        int c = bn0 + wn * 64 + ni * 16 + (l & 15);
                        const float4* fr = (const float4*)(Fx + (size_t)rg * K_DIM);
                        const float4* er = (const float4*)(Et + (size_t)c * K_DIM);
                        float ex = 0.f;
                        for (int k4 = 0; k4 < 64; ++k4) {
                            float4 a = fr[k4], b = er[k4];
                            ex = fmaf(a.x, b.x, ex); ex = fmaf(a.y, b.y, ex);
                            ex = fmaf(a.z, b.z, ex); ex = fmaf(a.w, b.w, ex);
                        }
                        float dex = fmaf(-2.f, ex, nrmv[ni]);
                        atomicMin(&keysOut[rg], packKey(dex, c));
                    }
                }
            }
    }
}

// ---------------- gather + STE + diff + indices ----------------
__global__ void gather_kernel(const float* __restrict__ F,
                              const float* __restrict__ Et,
                              const unsigned long long* __restrict__ keys,
                              float* __restrict__ q_out,
                              float* __restrict__ diff_out,
                              float* __restrict__ ind_out) {
    const int l = threadIdx.x & 63;
    const int wave = blockIdx.x * 4 + (threadIdx.x >> 6);
    const int nw = gridDim.x * 4;
    float dsum = 0.f;
    for (int row = wave; row < M_ROWS; row += nw) {
        int ind = (int)(keys[row] & 0xFFFFFFFFull);
        if (l == 0) ind_out[row] = (float)ind;
        float4 x = *(const float4*)&F[(size_t)row * K_DIM + l * 4];
        float4 e = *(const float4*)&Et[(size_t)ind * K_DIM + l * 4];
        float dx = e.x - x.x, dy = e.y - x.y, dz = e.z - x.z, dw = e.w - x.w;
        float4 o = {x.x + dx, x.y + dy, x.z + dz, x.w + dw};
        *(float4*)&q_out[(size_t)row * K_DIM + l * 4] = o;
        dsum = fmaf(dx, dx, dsum); dsum = fmaf(dy, dy, dsum);
        dsum = fmaf(dz, dz, dsum); dsum = fmaf(dw, dw, dsum);
    }
#pragma unroll
    for (int sh = 32; sh >= 1; sh >>= 1) dsum += __shfl_xor(dsum, sh, 64);
    if (l == 0)
        atomicAdd(diff_out, dsum * (1.0f / ((float)M_ROWS * (float)K_DIM)));
}

// ======================= LEGACY f32 fallback (round-1) =======================
__global__ void norms_kernel(const float* __restrict__ E, float* __restrict__ norms) {
    int j = blockIdx.x * blockDim.x + threadIdx.x;
    if (j >= N_CODES) return;
    float s = 0.f;
    for (int d = 0; d < K_DIM; ++d) {
        float v = E[(size_t)d * N_CODES + j];
        s = fmaf(v, v, s);
    }
    norms[j] = s;
}

__global__ __launch_bounds__(256, 2) void gemm_argmin_kernel(
    const float* __restrict__ F, const float* __restrict__ E,
    const float* __restrict__ norms, unsigned long long* __restrict__ keys) {
    __shared__ float As[32][132];
    __shared__ float Bs[32][132];
    const int bx = blockIdx.x & 31, by = blockIdx.x >> 5;
    const int bm0 = by * 128, bn0 = bx * 128;
    const int tid = threadIdx.x;
    const int tx = tid & 15, ty = tid >> 4;
    float acc[8][8];
#pragma unroll
    for (int i = 0; i < 8; ++i)
#pragma unroll
        for (int j = 0; j < 8; ++j) acc[i][j] = 0.f;
    for (int kc = 0; kc < K_DIM; kc += 32) {
        float4 a_reg[4], b_reg[4];
#pragma unroll
        for (int i = 0; i < 4; ++i) {
            int idx = tid + i * 256;
            int m = idx >> 3, k4 = idx & 7;
            a_reg[i] = *(const float4*)&F[(size_t)(bm0 + m) * K_DIM + kc + k4 * 4];
            int kk = idx >> 5, n4 = idx & 31;
            b_reg[i] = *(const float4*)&E[(size_t)(kc + kk) * N_CODES + bn0 + n4 * 4];
        }
        __syncthreads();
#pragma unroll
        for (int i = 0; i < 4; ++i) {
            int idx = tid + i * 256;
            int m = idx >> 3, k4 = idx & 7;
            As[k4 * 4 + 0][m] = a_reg[i].x; As[k4 * 4 + 1][m] = a_reg[i].y;
            As[k4 * 4 + 2][m] = a_reg[i].z; As[k4 * 4 + 3][m] = a_reg[i].w;
            int kk = idx >> 5, n4 = idx & 31;
            *(float4*)&Bs[kk][n4 * 4] = b_reg[i];
        }
        __syncthreads();
#pragma unroll
        for (int k = 0; k < 32; ++k) {
            float a[8], b[8];
            *(float4*)&a[0] = *(const float4*)&As[k][ty * 8];
            *(float4*)&a[4] = *(const float4*)&As[k][ty * 8 + 4];
            *(float4*)&b[0] = *(const float4*)&Bs[k][tx * 8];
            *(float4*)&b[4] = *(const float4*)&Bs[k][tx * 8 + 4];
#pragma unroll
            for (int i = 0; i < 8; ++i)
#pragma unroll
                for (int j = 0; j < 8; ++j) acc[i][j] = fmaf(a[i], b[j], acc[i][j]);
        }
    }
    float nrm8[8];
#pragma unroll
    for (int j = 0; j < 8; ++j) nrm8[j] = norms[bn0 + tx * 8 + j];
#pragma unroll
    for (int i = 0; i < 8; ++i) {
        float best = INFINITY; int bestj = 0;
#pragma unroll
        for (int j = 0; j < 8; ++j) {
            float d = fmaf(-2.f, acc[i][j], nrm8[j]);
            if (d < best) { best = d; bestj = bn0 + tx * 8 + j; }
        }
        unsigned long long key = packKey(best, bestj);
#pragma unroll
        for (int s = 1; s < 16; s <<= 1) {
            unsigned long long o = __shfl_xor(key, s, 64);
            if (o < key) key = o;
        }
        if (tx == 0) atomicMin(&keys[bm0 + ty * 8 + i], key);
    }
}

__global__ void gather_legacy_kernel(
    const float* __restrict__ F, const float* __restrict__ E,
    const unsigned long long* __restrict__ keys,
    float* __restrict__ q_out, float* __restrict__ diff_out,
    float* __restrict__ ind_out) {
    const int lane = threadIdx.x & 63;
    const int wave = (blockIdx.x * (blockDim.x >> 6)) + (threadIdx.x >> 6);
    const int nwaves = gridDim.x * (blockDim.x >> 6);
    float dsum = 0.f;
    for (int row = wave; row < M_ROWS; row += nwaves) {
        int ind = (int)(keys[row] & 0xFFFFFFFFull);
        if (lane == 0) ind_out[row] = (float)ind;
#pragma unroll
        for (int t = 0; t < 4; ++t) {
            int d = lane + t * 64;
            float x = F[(size_t)row * K_DIM + d];
            float q = E[(size_t)d * N_CODES + ind];
            float delta = q - x;
            q_out[(size_t)row * K_DIM + d] = x + delta;
            dsum = fmaf(delta, delta, dsum);
        }
    }
#pragma unroll
    for (int s = 32; s >= 1; s >>= 1) dsum += __shfl_xor(dsum, s, 64);
    if (lane == 0)
        atomicAdd(diff_out, dsum * (1.0f / ((float)M_ROWS * (float)K_DIM)));
}

// ============================== launch ==============================
extern "C" void kernel_launch(void* const* d_in, const int* in_sizes, int n_in,
                              void* d_out, int out_size, void* d_ws, size_t ws_size,
                              hipStream_t stream) {
    const float* F = (const float*)d_in[0];
    const float* E = (const float*)d_in[1];

    float* q_out = (float*)d_out;
    float* diff_out = q_out + (size_t)M_ROWS * K_DIM;
    float* ind_out = diff_out + 1;

    // ws layout (bytes)
    const size_t off_nrm = 0;             // 16 KB
    const size_t off_thr = 16384;         // 128 KB
    const size_t off_mx = 147456;         // 256 B
    const size_t off_k1 = 147712;         // 256 KB
    const size_t off_k2 = 409856;         // 256 KB
    const size_t off_Et = 672768;         // 4 MB   (16B aligned)
    const size_t off_Ethi = 4867072;      // 2 MB
    const size_t off_Fhi = 6964224;       // 16 MB
    const size_t NEED = 23741440;

    if (ws_size >= NEED) {
        float* nrm = (float*)((char*)d_ws + off_nrm);
        float* thrAdd = (float*)((char*)d_ws + off_thr);
        float* maxnrm = (float*)((char*)d_ws + off_mx);
        unsigned long long* keysA = (unsigned long long*)((char*)d_ws + off_k1);
        unsigned long long* keysB = (unsigned long long*)((char*)d_ws + off_k2);
        float* Et = (float*)((char*)d_ws + off_Et);
        unsigned short* Ethi = (unsigned short*)((char*)d_ws + off_Ethi);
        unsigned short* Fhi = (unsigned short*)((char*)d_ws + off_Fhi);

        hipMemsetAsync(keysA, 0xFF, 2 * (size_t)M_ROWS * 8, stream);  // keysA+keysB
        hipMemsetAsync(maxnrm, 0, 4, stream);
        hipMemsetAsync(diff_out, 0, 4, stream);

        transpose_kernel<<<256, 256, 0, stream>>>(E, Et, Ethi);
        nrm_et_kernel<<<1024, 256, 0, stream>>>(Et, nrm, maxnrm);
        splitF_kernel<<<8192, 256, 0, stream>>>(F, Fhi, thrAdd, maxnrm);
        gemm_bf16_kernel<1><<<8192, 256, 0, stream>>>(
            Fhi, Ethi, nrm, thrAdd, keysA, keysA, F, Et);
        gemm_bf16_kernel<2><<<8192, 256, 0, stream>>>(
            Fhi, Ethi, nrm, thrAdd, keysA, keysB, F, Et);
        gather_kernel<<<2048, 256, 0, stream>>>(F, Et, keysB, q_out, diff_out, ind_out);
    } else {
        // legacy f32 path
        float* norms = (float*)d_ws;
        unsigned long long* keys = (unsigned long long*)((char*)d_ws + 16384);
        hipMemsetAsync(keys, 0xFF, (size_t)M_ROWS * 8, stream);
        hipMemsetAsync(diff_out, 0, 4, stream);
        norms_kernel<<<N_CODES / 256, 256, 0, stream>>>(E, norms);
        gemm_argmin_kernel<<<(M_ROWS / 128) * (N_CODES / 128), 256, 0, stream>>>(F, E, norms, keys);
        gather_legacy_kernel<<<1024, 256, 0, stream>>>(F, E, keys, q_out, diff_out, ind_out);
    }
}

// Round 5
// 825.549 us; speedup vs baseline: 1.2566x; 1.2566x over previous
//
#include <hip/hip_runtime.h>
#include <hip/hip_bf16.h>

// VQ quantize. input [8,64,64,256] f32 -> flatten [M=32768, K=256]
// embed [K=256, N=4096] f32. Outputs in d_out (f32):
//   quantize [8388608], diff [1], embed_ind [32768] (as float)
//
// bf16-MFMA GEMM (256x256 tile, SINGLE-buffered round-2-proven sync
// discipline) stores top-2 approx keys per (row, 128-code group).
// Rescore: rigorous threshold window -> per-lane SERIAL exact f32 chains
// (bit-matching rounds 1/2) -> argmin, gather, STE, diff.

#define M_ROWS 32768
#define K_DIM 256
#define N_CODES 4096

typedef __attribute__((ext_vector_type(8))) short short8v;
typedef __attribute__((ext_vector_type(4))) float f32x4;

__device__ inline unsigned long long packKey(float d, int idx) {
    unsigned u = __float_as_uint(d);
    u = (u & 0x80000000u) ? ~u : (u | 0x80000000u);
    return ((unsigned long long)u << 32) | (unsigned)idx;
}
__device__ inline float unpackDist(unsigned long long k) {
    unsigned u = (unsigned)(k >> 32);
    u = (u & 0x80000000u) ? (u & 0x7FFFFFFFu) : ~u;
    return __uint_as_float(u);
}
__device__ inline unsigned short f2bf(float x) {
    __hip_bfloat16 h = __float2bfloat16(x);
    return *reinterpret_cast<unsigned short*>(&h);
}
__device__ inline unsigned long long u64min(unsigned long long a, unsigned long long b) {
    return a < b ? a : b;
}
__device__ inline unsigned long long u64max(unsigned long long a, unsigned long long b) {
    return a > b ? a : b;
}

// Round-1/2-proven serial exact dot: ascending k, float4, fmaf x,y,z,w.
__device__ inline float serial_dot(const float4* __restrict__ fr,
                                   const float4* __restrict__ er) {
    float ex = 0.f;
    for (int k4 = 0; k4 < 64; ++k4) {
        float4 a = fr[k4], b = er[k4];
        ex = fmaf(a.x, b.x, ex); ex = fmaf(a.y, b.y, ex);
        ex = fmaf(a.z, b.z, ex); ex = fmaf(a.w, b.w, ex);
    }
    return ex;
}

// ---------------- transpose E -> Et [N][K] f32 + Ethi [N][K] bf16 ----------
__global__ void transpose_kernel(const float* __restrict__ E,
                                 float* __restrict__ Et,
                                 unsigned short* __restrict__ Ethi) {
    __shared__ float tile[64][65];
    const int kb = blockIdx.x & 3;
    const int jb = blockIdx.x >> 2;
    const int t = threadIdx.x;
#pragma unroll
    for (int it = 0; it < 16; ++it) {
        int linear = it * 256 + t;
        int kk = linear >> 6, jj = linear & 63;
        tile[kk][jj] = E[(size_t)(kb * 64 + kk) * N_CODES + jb * 64 + jj];
    }
    __syncthreads();
#pragma unroll
    for (int it = 0; it < 16; ++it) {
        int linear = it * 256 + t;
        int jj = linear >> 6, kk = linear & 63;
        float v = tile[kk][jj];
        size_t o = (size_t)(jb * 64 + jj) * K_DIM + kb * 64 + kk;
        Et[o] = v;
        Ethi[o] = f2bf(v);
    }
}

// ---------------- norms from Et + max norm ----------------
__global__ void nrm_et_kernel(const float* __restrict__ Et,
                              float* __restrict__ nrm,
                              float* __restrict__ maxnrm) {
    const int l = threadIdx.x & 63;
    const int j = blockIdx.x * 4 + (threadIdx.x >> 6);
    float4 v = *(const float4*)&Et[(size_t)j * K_DIM + l * 4];
    float s = v.x * v.x;
    s = fmaf(v.y, v.y, s); s = fmaf(v.z, v.z, s); s = fmaf(v.w, v.w, s);
#pragma unroll
    for (int sh = 32; sh >= 1; sh >>= 1) s += __shfl_xor(s, sh, 64);
    if (l == 0) {
        nrm[j] = s;
        atomicMax((int*)maxnrm, __float_as_int(s));  // positive floats
    }
}

// ---------------- bf16 MFMA GEMM, 256x256 tile, top-2 epilogue -------------
// 8 waves (4x2): wave tile 64 rows x 128 cols. BK=64.
// SINGLE-buffered, round-2-proven sync order per K-step:
//   load A->regs | barrier (prev compute done) | write A-LDS + issue B
//   gload_lds | barrier (drains vmcnt+lgkm) | compute.
// A: reg-staged f32->bf16, chunk XOR-swizzle phys = c ^ (row&7).
// B: global_load_lds w=16, pre-swizzled global source (same involution).
__global__ __launch_bounds__(512) void gemm_top2_kernel(
    const float* __restrict__ F,              // [M][K] f32
    const unsigned short* __restrict__ Ethi,  // [N][K] bf16
    const float* __restrict__ nrm,            // [N]
    unsigned long long* __restrict__ keys2)   // [M][32][2]
{
    __shared__ unsigned short sA[256 * 64];
    __shared__ unsigned short sB[256 * 64];
    const int tid = threadIdx.x;
    const int l = tid & 63;
    const int wid = tid >> 6;
    // bijective XCD swizzle: 2048 blocks = 8 xcd * 256
    const int tile = (blockIdx.x & 7) * 256 + (blockIdx.x >> 3);
    const int by = tile >> 4, bx = tile & 15;
    const int bm0 = by * 256, bn0 = bx * 256;
    const int wm = wid >> 1, wn = wid & 1;

    f32x4 acc[4][8];
#pragma unroll
    for (int mi = 0; mi < 4; ++mi)
#pragma unroll
        for (int ni = 0; ni < 8; ++ni) acc[mi][ni] = (f32x4){0.f, 0.f, 0.f, 0.f};

    const float* aSrc = F + (size_t)(bm0 + wid * 32 + (l >> 1)) * K_DIM + (l & 1) * 32;
    const int arow = wid * 32 + (l >> 1);

#pragma unroll
    for (int kt = 0; kt < 4; ++kt) {
        // ---- load A chunk into regs (no LDS touch yet) ----
        float4 areg[8];
#pragma unroll
        for (int i = 0; i < 8; ++i)
            areg[i] = *(const float4*)(aSrc + kt * 64 + i * 4);

        if (kt > 0) __syncthreads();   // all waves done reading LDS

        // ---- write A to LDS (swizzled) ----
#pragma unroll
        for (int j = 0; j < 4; ++j) {
            short8v hv;
            hv[0] = (short)f2bf(areg[2 * j].x);     hv[1] = (short)f2bf(areg[2 * j].y);
            hv[2] = (short)f2bf(areg[2 * j].z);     hv[3] = (short)f2bf(areg[2 * j].w);
            hv[4] = (short)f2bf(areg[2 * j + 1].x); hv[5] = (short)f2bf(areg[2 * j + 1].y);
            hv[6] = (short)f2bf(areg[2 * j + 1].z); hv[7] = (short)f2bf(areg[2 * j + 1].w);
            int c = (l & 1) * 4 + j, phys = c ^ (arow & 7);
            *(short8v*)&sA[arow * 64 + phys * 8] = hv;
        }
        // ---- issue B direct-to-LDS ----
#pragma unroll
        for (int i = 0; i < 4; ++i) {
            int q = wid * 4 + i;
            const unsigned short* src = Ethi +
                (size_t)(bn0 + q * 8 + (l >> 3)) * K_DIM + kt * 64 +
                ((l & 7) ^ (l >> 3)) * 8;
            __builtin_amdgcn_global_load_lds(
                (const __attribute__((address_space(1))) unsigned int*)src,
                (__attribute__((address_space(3))) unsigned int*)&sB[q * 512],
                16, 0, 0);
        }
        __syncthreads();   // compiler drains vmcnt(0)+lgkmcnt(0) before barrier

        // ---- compute two 32-k slices ----
#pragma unroll
        for (int s = 0; s < 2; ++s) {
            const int ch = s * 4 + (l >> 4);
            short8v af[4], bfv[8];
#pragma unroll
            for (int mi = 0; mi < 4; ++mi) {
                int r = wm * 64 + mi * 16 + (l & 15);
                af[mi] = *(const short8v*)&sA[r * 64 + (ch ^ (r & 7)) * 8];
            }
#pragma unroll
            for (int ni = 0; ni < 8; ++ni) {
                int c = wn * 128 + ni * 16 + (l & 15);
                bfv[ni] = *(const short8v*)&sB[c * 64 + (ch ^ (c & 7)) * 8];
            }
#pragma unroll
            for (int mi = 0; mi < 4; ++mi)
#pragma unroll
                for (int ni = 0; ni < 8; ++ni)
                    acc[mi][ni] = __builtin_amdgcn_mfma_f32_16x16x32_bf16(
                        af[mi], bfv[ni], acc[mi][ni], 0, 0, 0);
        }
    }

    // ---- epilogue: top-2 per (row, this wave's 128 codes) ----
    float nv[8];
#pragma unroll
    for (int ni = 0; ni < 8; ++ni)
        nv[ni] = nrm[bn0 + wn * 128 + ni * 16 + (l & 15)];

#pragma unroll
    for (int mi = 0; mi < 4; ++mi)
#pragma unroll
        for (int rr = 0; rr < 4; ++rr) {
            unsigned long long k1 = ~0ull, k2 = ~0ull;
#pragma unroll
            for (int ni = 0; ni < 8; ++ni) {
                float d = fmaf(-2.f, acc[mi][ni][rr], nv[ni]);
                unsigned long long kk =
                    packKey(d, bn0 + wn * 128 + ni * 16 + (l & 15));
                if (kk < k1) { k2 = k1; k1 = kk; }
                else if (kk < k2) { k2 = kk; }
            }
            // merge top-2 across the 16 lanes sharing this output row
#pragma unroll
            for (int st = 1; st < 16; st <<= 1) {
                unsigned long long o1 = __shfl_xor(k1, st, 64);
                unsigned long long o2 = __shfl_xor(k2, st, 64);
                unsigned long long hi = u64max(k1, o1);
                k1 = u64min(k1, o1);
                k2 = u64min(u64min(k2, o2), hi);
            }
            if ((l & 15) == 0) {
                int row = bm0 + wm * 64 + mi * 16 + (l >> 4) * 4 + rr;
                int g = bx * 2 + wn;
                keys2[(size_t)row * 64 + g * 2]     = k1;
                keys2[(size_t)row * 64 + g * 2 + 1] = k2;
            }
        }
}

// ---------------- rescore: per-lane SERIAL exact chains (round-2 bits) -----
__global__ __launch_bounds__(256) void rescore_kernel(
    const float* __restrict__ F,
    const float* __restrict__ Et,
    const float* __restrict__ nrm,
    const float* __restrict__ maxnrm,
    const unsigned long long* __restrict__ keys2,
    float* __restrict__ q_out,
    float* __restrict__ diff_out,
    float* __restrict__ ind_out)
{
    __shared__ float wpart[4];
    const int l = threadIdx.x & 63;
    const int wid = threadIdx.x >> 6;
    const float mxn = maxnrm[0];
    float ldiff = 0.f;
    const int rbase = (blockIdx.x * 4 + wid) * 8;

    for (int rr = 0; rr < 8; ++rr) {
        const int row = rbase + rr;
        const unsigned long long* slots = keys2 + (size_t)row * 64;
        const float4* fr = (const float4*)&F[(size_t)row * K_DIM];

        unsigned long long k = slots[l];
        float dk = unpackDist(k);
        float m = dk;
#pragma unroll
        for (int s = 1; s < 64; s <<= 1) m = fminf(m, __shfl_xor(m, s, 64));
        float4 x4 = fr[l];
        float nx = x4.x * x4.x;
        nx = fmaf(x4.y, x4.y, nx); nx = fmaf(x4.z, x4.z, nx); nx = fmaf(x4.w, x4.w, nx);
#pragma unroll
        for (int s = 1; s < 64; s <<= 1) nx += __shfl_xor(nx, s, 64);
        // window: rigorous 2*Delta = 0.03125*||x||*maxE; use 1.6x + slack
        const float thr = m + 0.05f * sqrtf(nx * mxn) + 0.25f;

        const unsigned long long cm = __ballot(dk <= thr);
        unsigned long long bestk = ~0ull;

        // lane l takes the l-th set bit of cm: serial exact rescore
        {
            unsigned long long t = cm;
            for (int i = 0; i < l && t; ++i) t &= t - 1;
            if (t) {
                int b = __ffsll(t) - 1;
                int c = (int)(slots[b] & 0xffffffffull);
                float ex = serial_dot(fr, (const float4*)&Et[(size_t)c * K_DIM]);
                bestk = packKey(fmaf(-2.f, ex, nrm[c]), c);
            }
        }
        // fallback: groups whose stored rank-2 is within thr -> scan all 128
        unsigned long long fg = cm & 0xAAAAAAAAAAAAAAAAull;
        while (fg) {
            int b = __ffsll(fg) - 1;
            fg &= fg - 1;
            int g = b >> 1;
#pragma unroll
            for (int h = 0; h < 2; ++h) {
                int c = g * 128 + h * 64 + l;
                float ex = serial_dot(fr, (const float4*)&Et[(size_t)c * K_DIM]);
                bestk = u64min(bestk, packKey(fmaf(-2.f, ex, nrm[c]), c));
            }
        }
#pragma unroll
        for (int s = 1; s < 64; s <<= 1)
            bestk = u64min(bestk, __shfl_xor(bestk, s, 64));

        const unsigned cstar = (unsigned)(bestk & 0xffffffffull);
        float4 e4 = *(const float4*)&Et[(size_t)cstar * K_DIM + l * 4];
        float d0 = e4.x - x4.x, d1 = e4.y - x4.y, d2 = e4.z - x4.z, d3 = e4.w - x4.w;
        float4 o = {x4.x + d0, x4.y + d1, x4.z + d2, x4.w + d3};
        *(float4*)&q_out[(size_t)row * K_DIM + l * 4] = o;
        ldiff = fmaf(d0, d0, ldiff); ldiff = fmaf(d1, d1, ldiff);
        ldiff = fmaf(d2, d2, ldiff); ldiff = fmaf(d3, d3, ldiff);
        if (l == 0) ind_out[row] = (float)cstar;
    }
#pragma unroll
    for (int s = 1; s < 64; s <<= 1) ldiff += __shfl_xor(ldiff, s, 64);
    if (l == 0) wpart[wid] = ldiff;
    __syncthreads();
    if (threadIdx.x == 0) {
        float t = 0.f;
#pragma unroll
        for (int i = 0; i < 4; ++i) t += wpart[i];
        atomicAdd(diff_out, t * (1.0f / ((float)M_ROWS * (float)K_DIM)));
    }
}

// ======================= LEGACY f32 fallback (round-1, proven) ==============
__global__ void norms_kernel(const float* __restrict__ E, float* __restrict__ norms) {
    int j = blockIdx.x * blockDim.x + threadIdx.x;
    if (j >= N_CODES) return;
    float s = 0.f;
    for (int d = 0; d < K_DIM; ++d) {
        float v = E[(size_t)d * N_CODES + j];
        s = fmaf(v, v, s);
    }
    norms[j] = s;
}

__global__ __launch_bounds__(256, 2) void gemm_argmin_kernel(
    const float* __restrict__ F, const float* __restrict__ E,
    const float* __restrict__ norms, unsigned long long* __restrict__ keys) {
    __shared__ float As[32][132];
    __shared__ float Bs[32][132];
    const int bx = blockIdx.x & 31, by = blockIdx.x >> 5;
    const int bm0 = by * 128, bn0 = bx * 128;
    const int tid = threadIdx.x;
    const int tx = tid & 15, ty = tid >> 4;
    float acc[8][8];
#pragma unroll
    for (int i = 0; i < 8; ++i)
#pragma unroll
        for (int j = 0; j < 8; ++j) acc[i][j] = 0.f;
    for (int kc = 0; kc < K_DIM; kc += 32) {
        float4 a_reg[4], b_reg[4];
#pragma unroll
        for (int i = 0; i < 4; ++i) {
            int idx = tid + i * 256;
            int m = idx >> 3, k4 = idx & 7;
            a_reg[i] = *(const float4*)&F[(size_t)(bm0 + m) * K_DIM + kc + k4 * 4];
            int kk = idx >> 5, n4 = idx & 31;
            b_reg[i] = *(const float4*)&E[(size_t)(kc + kk) * N_CODES + bn0 + n4 * 4];
        }
        __syncthreads();
#pragma unroll
        for (int i = 0; i < 4; ++i) {
            int idx = tid + i * 256;
            int m = idx >> 3, k4 = idx & 7;
            As[k4 * 4 + 0][m] = a_reg[i].x; As[k4 * 4 + 1][m] = a_reg[i].y;
            As[k4 * 4 + 2][m] = a_reg[i].z; As[k4 * 4 + 3][m] = a_reg[i].w;
            int kk = idx >> 5, n4 = idx & 31;
            *(float4*)&Bs[kk][n4 * 4] = b_reg[i];
        }
        __syncthreads();
#pragma unroll
        for (int k = 0; k < 32; ++k) {
            float a[8], b[8];
            *(float4*)&a[0] = *(const float4*)&As[k][ty * 8];
            *(float4*)&a[4] = *(const float4*)&As[k][ty * 8 + 4];
            *(float4*)&b[0] = *(const float4*)&Bs[k][tx * 8];
            *(float4*)&b[4] = *(const float4*)&Bs[k][tx * 8 + 4];
#pragma unroll
            for (int i = 0; i < 8; ++i)
#pragma unroll
                for (int j = 0; j < 8; ++j) acc[i][j] = fmaf(a[i], b[j], acc[i][j]);
        }
    }
    float nrm8[8];
#pragma unroll
    for (int j = 0; j < 8; ++j) nrm8[j] = norms[bn0 + tx * 8 + j];
#pragma unroll
    for (int i = 0; i < 8; ++i) {
        float best = INFINITY; int bestj = 0;
#pragma unroll
        for (int j = 0; j < 8; ++j) {
            float d = fmaf(-2.f, acc[i][j], nrm8[j]);
            if (d < best) { best = d; bestj = bn0 + tx * 8 + j; }
        }
        unsigned long long key = packKey(best, bestj);
#pragma unroll
        for (int s = 1; s < 16; s <<= 1) {
            unsigned long long o = __shfl_xor(key, s, 64);
            if (o < key) key = o;
        }
        if (tx == 0) atomicMin(&keys[bm0 + ty * 8 + i], key);
    }
}

__global__ void gather_legacy_kernel(
    const float* __restrict__ F, const float* __restrict__ E,
    const unsigned long long* __restrict__ keys,
    float* __restrict__ q_out, float* __restrict__ diff_out,
    float* __restrict__ ind_out) {
    const int lane = threadIdx.x & 63;
    const int wave = (blockIdx.x * (blockDim.x >> 6)) + (threadIdx.x >> 6);
    const int nwaves = gridDim.x * (blockDim.x >> 6);
    float dsum = 0.f;
    for (int row = wave; row < M_ROWS; row += nwaves) {
        int ind = (int)(keys[row] & 0xFFFFFFFFull);
        if (lane == 0) ind_out[row] = (float)ind;
#pragma unroll
        for (int t = 0; t < 4; ++t) {
            int d = lane + t * 64;
            float x = F[(size_t)row * K_DIM + d];
            float q = E[(size_t)d * N_CODES + ind];
            float delta = q - x;
            q_out[(size_t)row * K_DIM + d] = x + delta;
            dsum = fmaf(delta, delta, dsum);
        }
    }
#pragma unroll
    for (int s = 32; s >= 1; s >>= 1) dsum += __shfl_xor(dsum, s, 64);
    if (lane == 0)
        atomicAdd(diff_out, dsum * (1.0f / ((float)M_ROWS * (float)K_DIM)));
}

// ============================== launch ==============================
extern "C" void kernel_launch(void* const* d_in, const int* in_sizes, int n_in,
                              void* d_out, int out_size, void* d_ws, size_t ws_size,
                              hipStream_t stream) {
    const float* F = (const float*)d_in[0];
    const float* E = (const float*)d_in[1];

    float* q_out = (float*)d_out;
    float* diff_out = q_out + (size_t)M_ROWS * K_DIM;
    float* ind_out = diff_out + 1;

    const size_t off_nrm  = 0;                       // 16 KB
    const size_t off_mx   = 16384;                   // 4 B
    const size_t off_Et   = 32768;                   // 4 MB
    const size_t off_Ethi = off_Et + (size_t)N_CODES * K_DIM * 4;    // 2 MB
    const size_t off_k2   = off_Ethi + (size_t)N_CODES * K_DIM * 2;  // 16 MB
    const size_t NEED     = off_k2 + (size_t)M_ROWS * 64 * 8;

    if (ws_size >= NEED) {
        float* nrm = (float*)((char*)d_ws + off_nrm);
        float* maxnrm = (float*)((char*)d_ws + off_mx);
        float* Et = (float*)((char*)d_ws + off_Et);
        unsigned short* Ethi = (unsigned short*)((char*)d_ws + off_Ethi);
        unsigned long long* keys2 = (unsigned long long*)((char*)d_ws + off_k2);

        hipMemsetAsync(maxnrm, 0, 4, stream);
        hipMemsetAsync(diff_out, 0, 4, stream);

        transpose_kernel<<<256, 256, 0, stream>>>(E, Et, Ethi);
        nrm_et_kernel<<<1024, 256, 0, stream>>>(Et, nrm, maxnrm);
        gemm_top2_kernel<<<2048, 512, 0, stream>>>(F, Ethi, nrm, keys2);
        rescore_kernel<<<1024, 256, 0, stream>>>(F, Et, nrm, maxnrm, keys2,
                                                 q_out, diff_out, ind_out);
    } else {
        float* norms = (float*)d_ws;
        unsigned long long* keys = (unsigned long long*)((char*)d_ws + 16384);
        hipMemsetAsync(keys, 0xFF, (size_t)M_ROWS * 8, stream);
        hipMemsetAsync(diff_out, 0, 4, stream);
        norms_kernel<<<N_CODES / 256, 256, 0, stream>>>(E, norms);
        gemm_argmin_kernel<<<(M_ROWS / 128) * (N_CODES / 128), 256, 0, stream>>>(F, E, norms, keys);
        gather_legacy_kernel<<<1024, 256, 0, stream>>>(F, E, keys, q_out, diff_out, ind_out);
    }
}